// Round 9
// baseline (66112.396 us; speedup 1.0000x reference)
//
#include <hip/hip_runtime.h>
#include <math.h>
#include <stdint.h>

#define SEQ   4096
#define NWG   256
#define NTHR  256
#define FINTAG 0x40000000u

// ws layout in dwords. Cells are 8B {f32 h, u32 tag}.
#define WS_BIG  0                    // big ring  [4][1536] cells
#define WS_SML  12288                // small ring [4][768] cells
#define WS_FIN  18432                // final cells [256]
#define WS_OUTP 18944                // outp [4096][256] f32
#define WS_ZERO WS_OUTP

typedef float f32x4 __attribute__((ext_vector_type(4)));

// fast, saturation-safe activations (v_exp_f32 / v_rcp_f32)
__device__ __forceinline__ float sigf(float x){
  float e = __builtin_amdgcn_exp2f(-1.44269504089f * x);   // exp(-x)
  return __builtin_amdgcn_rcpf(1.0f + e);
}
__device__ __forceinline__ float tanhf_fast(float x){
  float e = __builtin_amdgcn_exp2f(2.88539008178f * x);    // exp(2x)
  return 1.0f - 2.0f * __builtin_amdgcn_rcpf(e + 1.0f);    // +-inf-safe
}

__device__ __forceinline__ float wsum64(float v){
#pragma unroll
  for (int m = 32; m > 0; m >>= 1) v += __shfl_xor(v, m);
  return v;
}

__device__ __forceinline__ float g_load(const float* p){
  return __hip_atomic_load(p, __ATOMIC_RELAXED, __HIP_MEMORY_SCOPE_AGENT);
}
__device__ __forceinline__ void g_store(float* p, float v){
  __hip_atomic_store(p, v, __ATOMIC_RELAXED, __HIP_MEMORY_SCOPE_AGENT);
}
// single 8B atomic store: {h, tag} — data IS the signal
__device__ __forceinline__ void cell_store(float* cell, float h, unsigned tag){
  unsigned long long pk = ((unsigned long long)tag << 32) | (unsigned long long)__float_as_uint(h);
  __hip_atomic_store((unsigned long long*)cell, pk, __ATOMIC_RELAXED, __HIP_MEMORY_SCOPE_AGENT);
}

// pair-dot: fragment q lives in two dwordx4 regs A={h0,tag,h1,tag}, B={h2,tag,h3,tag}
#define DOTP(acc, wv4, A, B) \
  acc += (wv4)[0]*(A)[0] + (wv4)[1]*(A)[2] + (wv4)[2]*(B)[0] + (wv4)[3]*(B)[2];

// Every wave loads the FULL slot into registers: big cells 256q+4*lane+{0..3}
// (q=0..5) and small cells likewise (q=0..2). 18 dwordx4, tags embedded.
// Bases: pb0 (+0B), pb1 (+4096B), pb2 (+8192B), ps0 (+0B), ps1 (+4096B).
#define RETRY_ALL(pb0, pb1, pb2, ps0, ps1, tgv)                              \
  for(;;){                                                                   \
    asm volatile(                                                            \
      "global_load_dwordx4 %0,  %18, off sc0 sc1\n\t"                        \
      "global_load_dwordx4 %1,  %18, off offset:16 sc0 sc1\n\t"              \
      "global_load_dwordx4 %2,  %18, off offset:2048 sc0 sc1\n\t"            \
      "global_load_dwordx4 %3,  %18, off offset:2064 sc0 sc1\n\t"            \
      "global_load_dwordx4 %4,  %19, off sc0 sc1\n\t"                        \
      "global_load_dwordx4 %5,  %19, off offset:16 sc0 sc1\n\t"              \
      "global_load_dwordx4 %6,  %19, off offset:2048 sc0 sc1\n\t"            \
      "global_load_dwordx4 %7,  %19, off offset:2064 sc0 sc1\n\t"            \
      "global_load_dwordx4 %8,  %20, off sc0 sc1\n\t"                        \
      "global_load_dwordx4 %9,  %20, off offset:16 sc0 sc1\n\t"              \
      "global_load_dwordx4 %10, %20, off offset:2048 sc0 sc1\n\t"            \
      "global_load_dwordx4 %11, %20, off offset:2064 sc0 sc1\n\t"            \
      "global_load_dwordx4 %12, %21, off sc0 sc1\n\t"                        \
      "global_load_dwordx4 %13, %21, off offset:16 sc0 sc1\n\t"              \
      "global_load_dwordx4 %14, %21, off offset:2048 sc0 sc1\n\t"            \
      "global_load_dwordx4 %15, %21, off offset:2064 sc0 sc1\n\t"            \
      "global_load_dwordx4 %16, %22, off sc0 sc1\n\t"                        \
      "global_load_dwordx4 %17, %22, off offset:16 sc0 sc1\n\t"              \
      "s_waitcnt vmcnt(0)"                                                   \
      : "=&v"(BL[0]), "=&v"(BL[1]), "=&v"(BL[2]),  "=&v"(BL[3]),             \
        "=&v"(BL[4]), "=&v"(BL[5]), "=&v"(BL[6]),  "=&v"(BL[7]),             \
        "=&v"(BL[8]), "=&v"(BL[9]), "=&v"(BL[10]), "=&v"(BL[11]),            \
        "=&v"(SL[0]), "=&v"(SL[1]), "=&v"(SL[2]),  "=&v"(SL[3]),             \
        "=&v"(SL[4]), "=&v"(SL[5])                                           \
      : "v"(pb0), "v"(pb1), "v"(pb2), "v"(ps0), "v"(ps1)                     \
      : "memory");                                                           \
    const unsigned tgu = (unsigned)(tgv);                                    \
    bool ok = true;                                                          \
    _Pragma("unroll")                                                        \
    for (int i_ = 0; i_ < 12; ++i_)                                          \
      ok &= (__float_as_uint(BL[i_][1])==tgu) & (__float_as_uint(BL[i_][3])==tgu); \
    _Pragma("unroll")                                                        \
    for (int i_ = 0; i_ < 6; ++i_)                                           \
      ok &= (__float_as_uint(SL[i_][1])==tgu) & (__float_as_uint(SL[i_][3])==tgu); \
    if (__all(ok)) break;                                                    \
    __builtin_amdgcn_s_sleep(2);                                             \
  }

#define RETRY_SML(ps0, ps1, tgv)                                             \
  for(;;){                                                                   \
    asm volatile(                                                            \
      "global_load_dwordx4 %0, %6, off sc0 sc1\n\t"                          \
      "global_load_dwordx4 %1, %6, off offset:16 sc0 sc1\n\t"                \
      "global_load_dwordx4 %2, %6, off offset:2048 sc0 sc1\n\t"              \
      "global_load_dwordx4 %3, %6, off offset:2064 sc0 sc1\n\t"              \
      "global_load_dwordx4 %4, %7, off sc0 sc1\n\t"                          \
      "global_load_dwordx4 %5, %7, off offset:16 sc0 sc1\n\t"                \
      "s_waitcnt vmcnt(0)"                                                   \
      : "=&v"(SL[0]), "=&v"(SL[1]), "=&v"(SL[2]),                            \
        "=&v"(SL[3]), "=&v"(SL[4]), "=&v"(SL[5])                             \
      : "v"(ps0), "v"(ps1)                                                   \
      : "memory");                                                           \
    const unsigned tgu = (unsigned)(tgv);                                    \
    bool ok = true;                                                          \
    _Pragma("unroll")                                                        \
    for (int i_ = 0; i_ < 6; ++i_)                                           \
      ok &= (__float_as_uint(SL[i_][1])==tgu) & (__float_as_uint(SL[i_][3])==tgu); \
    if (__all(ok)) break;                                                    \
    __builtin_amdgcn_s_sleep(2);                                             \
  }

__global__ void init_ws(float* ws){
  int i = threadIdx.x + blockIdx.x*blockDim.x;
  for (; i < WS_ZERO; i += blockDim.x*gridDim.x)
    __hip_atomic_store(ws + i, 0.0f, __ATOMIC_RELAXED, __HIP_MEMORY_SCOPE_AGENT);
}

__global__ __launch_bounds__(NTHR, 1) void lstm_ae(
    const float* __restrict__ x,
    const float* __restrict__ e1Wih, const float* __restrict__ e1Whh,
    const float* __restrict__ e1bih, const float* __restrict__ e1bhh,
    const float* __restrict__ e2Wih, const float* __restrict__ e2Whh,
    const float* __restrict__ e2bih, const float* __restrict__ e2bhh,
    const float* __restrict__ d1Wih, const float* __restrict__ d1Whh,
    const float* __restrict__ d1bih, const float* __restrict__ d1bhh,
    const float* __restrict__ d2Wih, const float* __restrict__ d2Whh,
    const float* __restrict__ d2bih, const float* __restrict__ d2bhh,
    const float* __restrict__ outW, const float* __restrict__ outb,
    float* __restrict__ out, float* __restrict__ ws)
{
  const int w    = blockIdx.x;
  const int tid  = threadIdx.x;
  const int lane = tid & 63;
  const int v    = tid >> 6;          // wave 0..3 == gate index

  float* outp = ws + WS_OUTP;

  __shared__ float lx[SEQ];           // 16 KB input
  __shared__ float lgB[24], lgS[12];  // gate pre-activations [gate][unit]

  for (int i = tid; i < SEQ; i += NTHR) lx[i] = x[i];

  // ---- weights: gate-parallel mapping. wave v owns gate v of all units. ----
  // big rows: v*1536 + 6w + r (r=0..5). small rows: v*768 + 3w + r (r=0..2).
  // frag (q,j) multiplies h[256q + 4*lane + j].
  f32x4 wR[6][6];   // e1Whh -> d2Whh      (K=1536)
  f32x4 wA[18];     // e2Wih r*6+q (r<3) -> d2Wih r*3+q (r<6)
  f32x4 wB[9];      // e2Whh r*3+q -> d1Wih (Z) -> d1Whh (D)
  float wihB[6], biasB[6], biasS[3], zw[3], bz[3];

#pragma unroll
  for (int r = 0; r < 6; ++r){
    const int row = v*1536 + 6*w + r;
    const float* p = e1Whh + (size_t)row*1536 + 4*lane;
#pragma unroll
    for (int q = 0; q < 6; ++q) wR[r][q] = *(const f32x4*)(p + 256*q);
    wihB[r]  = e1Wih[row];
    biasB[r] = e1bih[row] + e1bhh[row];
  }
#pragma unroll
  for (int r = 0; r < 3; ++r){
    const int row = v*768 + 3*w + r;
    const float* pi = e2Wih + (size_t)row*1536 + 4*lane;
#pragma unroll
    for (int q = 0; q < 6; ++q) wA[r*6+q] = *(const f32x4*)(pi + 256*q);
    const float* ph = e2Whh + (size_t)row*768 + 4*lane;
#pragma unroll
    for (int q = 0; q < 3; ++q) wB[r*3+q] = *(const f32x4*)(ph + 256*q);
    biasS[r] = e2bih[row] + e2bhh[row];
  }

  float cB = 0.0f, cS = 0.0f;   // wave0 lanes 0-5: big cell state; lanes 8-10: small
  const float ob = outb[0];
  float ow = (v == 0 && lane < 6) ? outW[6*w + lane] : 0.0f;

  __syncthreads();   // lx staged

  // ================= Phase EN: iter g consumes packet g, produces g+1 =================
  for (int g = 0; g <= SEQ; ++g){
    const int slot = g & 3;
    f32x4 BL[12], SL[6];
    {
      const float* pb0 = ws + WS_BIG + slot*3072 + 8*lane;
      const float* ps0 = ws + WS_SML + slot*1536 + 8*lane;
      RETRY_ALL(pb0, pb0 + 1024, pb0 + 2048, ps0, ps0 + 1024, g);
    }

    float a0=0.f,a1=0.f,a2=0.f,a3=0.f,a4=0.f,a5=0.f;
    if (g < SEQ){      // e1: gate v of units 0..5 (input h1[g] = big)
#pragma unroll
      for (int q = 0; q < 6; ++q){
        DOTP(a0, wR[0][q], BL[2*q], BL[2*q+1]); DOTP(a1, wR[1][q], BL[2*q], BL[2*q+1]);
        DOTP(a2, wR[2][q], BL[2*q], BL[2*q+1]); DOTP(a3, wR[3][q], BL[2*q], BL[2*q+1]);
        DOTP(a4, wR[4][q], BL[2*q], BL[2*q+1]); DOTP(a5, wR[5][q], BL[2*q], BL[2*q+1]);
      }
      a0=wsum64(a0); a1=wsum64(a1); a2=wsum64(a2);
      a3=wsum64(a3); a4=wsum64(a4); a5=wsum64(a5);
    }
    float b0=0.f,b1=0.f,b2=0.f;
    if (g >= 1){       // e2: gate v of units 0..2 (input h1[g], state h2[g-1])
#pragma unroll
      for (int q = 0; q < 6; ++q){
        DOTP(b0, wA[0*6+q], BL[2*q], BL[2*q+1]);
        DOTP(b1, wA[1*6+q], BL[2*q], BL[2*q+1]);
        DOTP(b2, wA[2*6+q], BL[2*q], BL[2*q+1]);
      }
#pragma unroll
      for (int q = 0; q < 3; ++q){
        DOTP(b0, wB[0*3+q], SL[2*q], SL[2*q+1]);
        DOTP(b1, wB[1*3+q], SL[2*q], SL[2*q+1]);
        DOTP(b2, wB[2*3+q], SL[2*q], SL[2*q+1]);
      }
      b0=wsum64(b0); b1=wsum64(b1); b2=wsum64(b2);
    }
    if (lane == 0){
      if (g < SEQ){
        float xt = lx[g];
        lgB[v*6+0]=a0+wihB[0]*xt+biasB[0]; lgB[v*6+1]=a1+wihB[1]*xt+biasB[1];
        lgB[v*6+2]=a2+wihB[2]*xt+biasB[2]; lgB[v*6+3]=a3+wihB[3]*xt+biasB[3];
        lgB[v*6+4]=a4+wihB[4]*xt+biasB[4]; lgB[v*6+5]=a5+wihB[5]*xt+biasB[5];
      }
      if (g >= 1){
        lgS[v*3+0]=b0+biasS[0]; lgS[v*3+1]=b1+biasS[1]; lgS[v*3+2]=b2+biasS[2];
      }
    }
    __syncthreads();                   // S2

    if (v == 0){       // produce packet g+1 (each cell: one 8B store, no flags)
      float* nbig = ws + WS_BIG + ((g+1)&3)*3072;
      float* nsml = ws + WS_SML + ((g+1)&3)*1536;
      if (g < SEQ && lane < 6){
        float gi=lgB[lane],gf=lgB[6+lane],gg=lgB[12+lane],go=lgB[18+lane];
        cB = sigf(gf)*cB + sigf(gi)*tanhf_fast(gg);
        cell_store(nbig + (6*w+lane)*2, sigf(go)*tanhf_fast(cB), (unsigned)(g+1));
      }
      if (lane >= 8 && lane < 11){
        int u = lane - 8;
        float hv = 0.0f;
        if (g >= 1){
          float gi=lgS[u],gf=lgS[3+u],gg=lgS[6+u],go=lgS[9+u];
          cS = sigf(gf)*cS + sigf(gi)*tanhf_fast(gg);
          hv = sigf(go)*tanhf_fast(cS);
        }
        cell_store(nsml + (3*w+u)*2, hv, (unsigned)(g+1));  // g==0: zero state for packet 1
      }
    }
  }

  // ================= Phase Z: zW = d1_Wih @ z + bias (packet SEQ+1, small) =================
  {
#pragma unroll
    for (int r = 0; r < 3; ++r){
      const int row = v*768 + 3*w + r;
      const float* p = d1Wih + (size_t)row*768 + 4*lane;
#pragma unroll
      for (int q = 0; q < 3; ++q) wB[r*3+q] = *(const f32x4*)(p + 256*q);
      bz[r] = d1bih[row] + d1bhh[row];
    }
    const int tg = SEQ+1, slot = tg & 3;
    f32x4 SL[6];
    {
      const float* ps0 = ws + WS_SML + slot*1536 + 8*lane;
      RETRY_SML(ps0, ps0 + 1024, tg);
    }
    float z0=0.f,z1=0.f,z2=0.f;
#pragma unroll
    for (int q = 0; q < 3; ++q){
      DOTP(z0, wB[0*3+q], SL[2*q], SL[2*q+1]);
      DOTP(z1, wB[1*3+q], SL[2*q], SL[2*q+1]);
      DOTP(z2, wB[2*3+q], SL[2*q], SL[2*q+1]);
    }
    zw[0]=wsum64(z0)+bz[0]; zw[1]=wsum64(z1)+bz[1]; zw[2]=wsum64(z2)+bz[2];
  }

  // ---- D-phase weights ----
#pragma unroll
  for (int r = 0; r < 6; ++r){
    const int row = v*1536 + 6*w + r;
    const float* p = d2Whh + (size_t)row*1536 + 4*lane;
#pragma unroll
    for (int q = 0; q < 6; ++q) wR[r][q] = *(const f32x4*)(p + 256*q);
    const float* pi = d2Wih + (size_t)row*768 + 4*lane;
#pragma unroll
    for (int q = 0; q < 3; ++q) wA[r*3+q] = *(const f32x4*)(pi + 256*q);
    biasB[r] = d2bih[row] + d2bhh[row];
  }
#pragma unroll
  for (int r = 0; r < 3; ++r){
    const int row = v*768 + 3*w + r;
    const float* p = d1Whh + (size_t)row*768 + 4*lane;
#pragma unroll
    for (int q = 0; q < 3; ++q) wB[r*3+q] = *(const f32x4*)(p + 256*q);
  }
  cB = 0.0f; cS = 0.0f;

  // ================= Phase D: iter t consumes packet SEQ+1+t, produces +1 =================
  for (int t = 0; t <= SEQ; ++t){
    const int pc = SEQ+1+t, slot = pc & 3;
    f32x4 BL[12], SL[6];
    if (t >= 1){
      const float* pb0 = ws + WS_BIG + slot*3072 + 8*lane;
      const float* ps0 = ws + WS_SML + slot*1536 + 8*lane;
      RETRY_ALL(pb0, pb0 + 1024, pb0 + 2048, ps0, ps0 + 1024, pc);
    } else {
#pragma unroll
      for (int q = 0; q < 12; ++q) BL[q] = (f32x4)0.0f;
#pragma unroll
      for (int q = 0; q < 6;  ++q) SL[q] = (f32x4)0.0f;
    }

    float b0=0.f,b1=0.f,b2=0.f;
    if (t < SEQ){      // d1: gate v of units 0..2 (state hd1[t] = small)
#pragma unroll
      for (int q = 0; q < 3; ++q){
        DOTP(b0, wB[0*3+q], SL[2*q], SL[2*q+1]);
        DOTP(b1, wB[1*3+q], SL[2*q], SL[2*q+1]);
        DOTP(b2, wB[2*3+q], SL[2*q], SL[2*q+1]);
      }
      b0=wsum64(b0); b1=wsum64(b1); b2=wsum64(b2);
    }
    float a0=0.f,a1=0.f,a2=0.f,a3=0.f,a4=0.f,a5=0.f;
    if (t >= 1){       // d2: gate v of units 0..5 (state hd2[t-1]=big, input hd1[t]=small)
#pragma unroll
      for (int q = 0; q < 6; ++q){
        DOTP(a0, wR[0][q], BL[2*q], BL[2*q+1]); DOTP(a1, wR[1][q], BL[2*q], BL[2*q+1]);
        DOTP(a2, wR[2][q], BL[2*q], BL[2*q+1]); DOTP(a3, wR[3][q], BL[2*q], BL[2*q+1]);
        DOTP(a4, wR[4][q], BL[2*q], BL[2*q+1]); DOTP(a5, wR[5][q], BL[2*q], BL[2*q+1]);
      }
#pragma unroll
      for (int q = 0; q < 3; ++q){
        DOTP(a0, wA[0*3+q], SL[2*q], SL[2*q+1]); DOTP(a1, wA[1*3+q], SL[2*q], SL[2*q+1]);
        DOTP(a2, wA[2*3+q], SL[2*q], SL[2*q+1]); DOTP(a3, wA[3*3+q], SL[2*q], SL[2*q+1]);
        DOTP(a4, wA[4*3+q], SL[2*q], SL[2*q+1]); DOTP(a5, wA[5*3+q], SL[2*q], SL[2*q+1]);
      }
      a0=wsum64(a0); a1=wsum64(a1); a2=wsum64(a2);
      a3=wsum64(a3); a4=wsum64(a4); a5=wsum64(a5);
    }
    if (lane == 0){
      if (t < SEQ){
        lgS[v*3+0]=b0+zw[0]; lgS[v*3+1]=b1+zw[1]; lgS[v*3+2]=b2+zw[2];
      }
      if (t >= 1){
        lgB[v*6+0]=a0+biasB[0]; lgB[v*6+1]=a1+biasB[1]; lgB[v*6+2]=a2+biasB[2];
        lgB[v*6+3]=a3+biasB[3]; lgB[v*6+4]=a4+biasB[4]; lgB[v*6+5]=a5+biasB[5];
      }
    }
    __syncthreads();                   // S2

    if (v == 0){       // produce packet pc+1
      float* nbig = ws + WS_BIG + ((pc+1)&3)*3072;
      float* nsml = ws + WS_SML + ((pc+1)&3)*1536;
      if (t < SEQ && lane >= 8 && lane < 11){
        int u = lane - 8;
        float gi=lgS[u],gf=lgS[3+u],gg=lgS[6+u],go=lgS[9+u];
        cS = sigf(gf)*cS + sigf(gi)*tanhf_fast(gg);
        cell_store(nsml + (3*w+u)*2, sigf(go)*tanhf_fast(cS), (unsigned)(pc+1));
      }
      float vv = 0.0f;
      if (lane < 6){
        float hv = 0.0f;
        if (t >= 1){
          float gi=lgB[lane],gf=lgB[6+lane],gg=lgB[12+lane],go=lgB[18+lane];
          cB = sigf(gf)*cB + sigf(gi)*tanhf_fast(gg);
          hv = sigf(go)*tanhf_fast(cB);
          vv = hv * ow;
        }
        cell_store(nbig + (6*w+lane)*2, hv, (unsigned)(pc+1));  // t==0: hd2 zero state
      }
      if (t >= 1 && lane < 8){
        vv += __shfl_xor(vv,1); vv += __shfl_xor(vv,2); vv += __shfl_xor(vv,4);
        if (lane == 0) g_store(&outp[(size_t)(t-1)*NWG + w], vv);
      }
    }
  }

  // ================= Finalize + reduce =================
  if (v == 0){
    asm volatile("s_waitcnt vmcnt(0)" ::: "memory");   // all outp/cell stores acked
    if (lane == 0) cell_store(ws + WS_FIN + w*2, 0.0f, FINTAG);
    const float* fb = ws + WS_FIN + (4*lane)*2;
    f32x4 F0, F1;
    for(;;){
      asm volatile(
        "global_load_dwordx4 %0, %2, off sc0 sc1\n\t"
        "global_load_dwordx4 %1, %2, off offset:16 sc0 sc1\n\t"
        "s_waitcnt vmcnt(0)"
        : "=&v"(F0), "=&v"(F1) : "v"(fb) : "memory");
      bool ok = (__float_as_uint(F0[1])==FINTAG)&(__float_as_uint(F0[3])==FINTAG)
              & (__float_as_uint(F1[1])==FINTAG)&(__float_as_uint(F1[3])==FINTAG);
      if (__all(ok)) break;
      __builtin_amdgcn_s_sleep(2);
    }
  }
  __syncthreads();
  {
    const int tau = w*16 + (tid >> 4);
    const int s4  = tid & 15;
    float s = 0.f;
#pragma unroll
    for (int j = 0; j < 16; ++j) s += g_load(&outp[(size_t)tau*NWG + s4 + 16*j]);
    s += __shfl_xor(s,8); s += __shfl_xor(s,4); s += __shfl_xor(s,2); s += __shfl_xor(s,1);
    if (s4 == 0) out[tau] = s + ob;
  }
}

extern "C" void kernel_launch(void* const* d_in, const int* in_sizes, int n_in,
                              void* d_out, int out_size, void* d_ws, size_t ws_size,
                              hipStream_t stream){
  (void)in_sizes; (void)n_in; (void)out_size; (void)ws_size;
  const float* x     = (const float*)d_in[0];
  const float* e1Wih = (const float*)d_in[1];
  const float* e1Whh = (const float*)d_in[2];
  const float* e1bih = (const float*)d_in[3];
  const float* e1bhh = (const float*)d_in[4];
  const float* e2Wih = (const float*)d_in[5];
  const float* e2Whh = (const float*)d_in[6];
  const float* e2bih = (const float*)d_in[7];
  const float* e2bhh = (const float*)d_in[8];
  const float* d1Wih = (const float*)d_in[9];
  const float* d1Whh = (const float*)d_in[10];
  const float* d1bih = (const float*)d_in[11];
  const float* d1bhh = (const float*)d_in[12];
  const float* d2Wih = (const float*)d_in[13];
  const float* d2Whh = (const float*)d_in[14];
  const float* d2bih = (const float*)d_in[15];
  const float* d2bhh = (const float*)d_in[16];
  const float* outW  = (const float*)d_in[17];
  const float* outb  = (const float*)d_in[18];
  float* out = (float*)d_out;
  float* ws  = (float*)d_ws;

  hipLaunchKernelGGL(init_ws, dim3(32), dim3(256), 0, stream, ws);

  // Plain launch (NOT cooperative): co-residency follows from grid == #CUs
  // at 1 block/CU (high-VGPR kernel); cooperative launch rejects this config.
  hipLaunchKernelGGL(lstm_ae, dim3(NWG), dim3(NTHR), 0, stream,
                     x,
                     e1Wih, e1Whh, e1bih, e1bhh,
                     e2Wih, e2Whh, e2bih, e2bhh,
                     d1Wih, d1Whh, d1bih, d1bhh,
                     d2Wih, d2Whh, d2bih, d2bhh,
                     outW,  outb,  out,   ws);
}